// Round 2
// baseline (12870.087 us; speedup 1.0000x reference)
//
#include <hip/hip_runtime.h>

#define T_DIM 256
#define B_DIM 128
#define C_DIM 512
#define H_DIM 512

typedef _Float16 half8 __attribute__((ext_vector_type(8)));
typedef float f32x4 __attribute__((ext_vector_type(4)));

// LDS: A-tile 32 ksteps x 16 rows x 80B (pad 64->80 breaks bank conflicts) = 40960 B
//      C-tile 16 x 65 floats = 4160 B
#define A_KS 640   // halfs per kstep
#define A_RS 40    // halfs per row
#define C_ST 65    // floats per row

__device__ __forceinline__ float sigf(float x) { return 1.0f / (1.0f + __expf(-x)); }
__device__ __forceinline__ float tanhf_(float x) {
  float e = __expf(2.0f * x);
  return (e - 1.0f) / (e + 1.0f);
}

__device__ __forceinline__ half8 cvt8(float4 a, float4 b) {
  half8 h;
  h[0] = (_Float16)a.x; h[1] = (_Float16)a.y; h[2] = (_Float16)a.z; h[3] = (_Float16)a.w;
  h[4] = (_Float16)b.x; h[5] = (_Float16)b.y; h[6] = (_Float16)b.z; h[7] = (_Float16)b.w;
  return h;
}

// Group-scope (32-block) barrier, monotonic counter, agent-scope release/acquire
// (compiler emits the cross-XCD L2 writeback/invalidate cache ops). Bounded spin
// so a co-residency failure degrades to wrong-answer instead of a hang.
__device__ __forceinline__ void gbar(unsigned* cnt, unsigned target) {
  __syncthreads();  // drains all waves' vmem (compiler emits vmcnt(0) pre-barrier)
  if (threadIdx.x == 0) {
    __hip_atomic_fetch_add(cnt, 1u, __ATOMIC_RELEASE, __HIP_MEMORY_SCOPE_AGENT);
    long long t0 = wall_clock64();
    while (__hip_atomic_load(cnt, __ATOMIC_RELAXED, __HIP_MEMORY_SCOPE_AGENT) < target) {
      if (wall_clock64() - t0 > 300000000LL) break;  // ~3s @100MHz anti-hang
    }
    (void)__hip_atomic_load(cnt, __ATOMIC_ACQUIRE, __HIP_MEMORY_SCOPE_AGENT);
  }
  __syncthreads();
}

// Persistent nested-LSTM. Grid 256 blocks x 256 threads, 1 block/CU.
// 8 groups (blockIdx&7) of 32 blocks; group g owns batch rows [16g,16g+16).
// Block bc=blockIdx>>3 owns gate cols j' in [16bc,16bc+16) -> 64 gate rows
// (4 gates x 16 j'); weights live in VGPRs as fp16 B-frags (256 regs/lane).
// Wave w computes gate w. Layer-0 h output goes to d_out (fp32) and is read
// back as layer-1 input, then overwritten by layer-1 h. States c,ci fp32 in
// regs of thread (b=tid&15, j'=tid>>4). Reference carry: next c = hi_n.
// hibuf is ping-pong buffered on t-parity (write (t+1)&1, read t&1) because
// its read (staging-2) and write (pointwise-2) share a barrier window.
__global__ __launch_bounds__(256, 1) void nlstm_pers(
    const float* __restrict__ xin, const float* __restrict__ h0,
    const float* __restrict__ Wg, const float* __restrict__ bgb,
    const float* __restrict__ Wi, const float* __restrict__ bib,
    float* __restrict__ out, unsigned* __restrict__ bar,
    _Float16* __restrict__ hbuf, _Float16* __restrict__ hibuf,
    _Float16* __restrict__ cellbuf)
{
  __shared__ __align__(16) char smem[45120];
  _Float16* Alds = (_Float16*)smem;
  float* Clds = (float*)(smem + 40960);

  const int tid  = threadIdx.x;
  const int grp  = blockIdx.x & 7;
  const int bc   = blockIdx.x >> 3;
  const int wv   = tid >> 6;       // wave = gate index q
  const int lane = tid & 63;
  const int ln   = lane & 15;      // MFMA n / m lane index
  const int kg   = lane >> 4;      // MFMA k-group
  const int srow = lane >> 2;      // staging row 0..15
  const int squd = lane & 3;       // staging quad 0..3
  const int pb   = tid & 15;       // pointwise batch row (in group)
  const int pj   = tid >> 4;       // pointwise j' local 0..15
  const int brow = grp * 16 + pb;  // global batch row
  const int jglob = bc * 16 + pj;  // global j' 0..511
  const int ncol  = bc * 16 + ln;  // weight column for this lane

  unsigned* cnt = bar + grp * 32;
  unsigned bseq = 0;

  half8 wgf[32], wif[32];
  float st_c = 0.f, st_ci = 0.f, o_pre = 0.f;
  float bgv[4], biv[4];

  for (int l = 0; l < 2; ++l) {
    // ---- layer init: weights -> VGPR fp16 frags ----
    const float* wgrow = Wg + ((size_t)l * 2048 + wv * 512 + ncol) * 1024;
    const float* wirow = Wi + ((size_t)l * 2048 + wv * 512 + ncol) * 1024;
#pragma unroll
    for (int ks = 0; ks < 32; ++ks) {
      const float* p = wgrow + ks * 32 + kg * 8;
      wgf[ks] = cvt8(*(const float4*)p, *(const float4*)(p + 4));
      const float* q = wirow + ks * 32 + kg * 8;
      wif[ks] = cvt8(*(const float4*)q, *(const float4*)(q + 4));
    }
#pragma unroll
    for (int q = 0; q < 4; ++q) {
      bgv[q] = bgb[l * 2048 + q * 512 + jglob];
      biv[q] = bib[l * 2048 + q * 512 + jglob];
    }
    // states: h0[l] layout (h, c, h_inner, c_inner) each [B,H]
    const float* h0l = h0 + (size_t)l * 4 * B_DIM * H_DIM + (size_t)brow * H_DIM + jglob;
    float h_in  = h0l[0];
    st_c        = h0l[(size_t)1 * B_DIM * H_DIM];
    float hi_in = h0l[(size_t)2 * B_DIM * H_DIM];
    st_ci       = h0l[(size_t)3 * B_DIM * H_DIM];
    hbuf [(size_t)brow * H_DIM + jglob] = (_Float16)h_in;
    hibuf[(size_t)brow * H_DIM + jglob] = (_Float16)hi_in;  // t=0 reads parity 0
    gbar(cnt, 32u * (++bseq));

    for (int t = 0; t < T_DIM; ++t) {
      // ================= phase 1: g = [x_t | h] @ Wg^T =================
      {
        const int ks0 = wv * 8;
#pragma unroll
        for (int i = 0; i < 8; ++i) {
          const int ks = ks0 + i;
          _Float16* dst = Alds + ks * A_KS + srow * A_RS + squd * 8;
          if (ks < 16) {  // x-part (cols 0..511): layer0 = xin, layer1 = out (y0)
            const int col = ks * 32 + squd * 8;
            const float* p = (l == 0)
                ? xin + ((size_t)t * B_DIM + grp * 16 + srow) * C_DIM + col
                : out + ((size_t)t * B_DIM + grp * 16 + srow) * H_DIM + col;
            *(half8*)dst = cvt8(*(const float4*)p, *(const float4*)(p + 4));
          } else {        // h-part (cols 512..1023)
            const int col = (ks - 16) * 32 + squd * 8;
            const _Float16* p = hbuf + (size_t)(grp * 16 + srow) * H_DIM + col;
            *(uint4*)dst = *(const uint4*)p;
          }
        }
      }
      __syncthreads();
      {
        f32x4 acc[4];
#pragma unroll
        for (int i = 0; i < 4; ++i) acc[i] = (f32x4){0.f, 0.f, 0.f, 0.f};
#pragma unroll
        for (int ks = 0; ks < 32; ++ks) {
          half8 a = *(const half8*)(Alds + ks * A_KS + ln * A_RS + kg * 8);
          acc[ks & 3] = __builtin_amdgcn_mfma_f32_16x16x32_f16(a, wgf[ks], acc[ks & 3], 0, 0, 0);
        }
        f32x4 r = acc[0] + acc[1] + acc[2] + acc[3];
#pragma unroll
        for (int rr = 0; rr < 4; ++rr)
          Clds[(kg * 4 + rr) * C_ST + wv * 16 + ln] = r[rr];
      }
      __syncthreads();
      {  // pointwise 1: cell = sig(f)*c + sig(i)*tanh(gc); stash o
        float gi = Clds[pb * C_ST + 0 * 16 + pj] + bgv[0];
        float gf = Clds[pb * C_ST + 1 * 16 + pj] + bgv[1];
        float go = Clds[pb * C_ST + 2 * 16 + pj] + bgv[2];
        float gc = Clds[pb * C_ST + 3 * 16 + pj] + bgv[3];
        float cell = sigf(gf) * st_c + sigf(gi) * tanhf_(gc);
        o_pre = go;
        cellbuf[(size_t)brow * H_DIM + jglob] = (_Float16)cell;
      }
      gbar(cnt, 32u * (++bseq));  // cell visible group-wide

      // ================= phase 2: g2 = [cell | hi] @ Wi^T =================
      {
        const _Float16* hird = hibuf + (size_t)(t & 1) * B_DIM * H_DIM;  // read parity
        const int ks0 = wv * 8;
#pragma unroll
        for (int i = 0; i < 8; ++i) {
          const int ks = ks0 + i;
          _Float16* dst = Alds + ks * A_KS + srow * A_RS + squd * 8;
          const _Float16* p = (ks < 16)
              ? cellbuf + (size_t)(grp * 16 + srow) * H_DIM + ks * 32 + squd * 8
              : hird    + (size_t)(grp * 16 + srow) * H_DIM + (ks - 16) * 32 + squd * 8;
          *(uint4*)dst = *(const uint4*)p;
        }
      }
      __syncthreads();
      {
        f32x4 acc[4];
#pragma unroll
        for (int i = 0; i < 4; ++i) acc[i] = (f32x4){0.f, 0.f, 0.f, 0.f};
#pragma unroll
        for (int ks = 0; ks < 32; ++ks) {
          half8 a = *(const half8*)(Alds + ks * A_KS + ln * A_RS + kg * 8);
          acc[ks & 3] = __builtin_amdgcn_mfma_f32_16x16x32_f16(a, wif[ks], acc[ks & 3], 0, 0, 0);
        }
        f32x4 r = acc[0] + acc[1] + acc[2] + acc[3];
#pragma unroll
        for (int rr = 0; rr < 4; ++rr)
          Clds[(kg * 4 + rr) * C_ST + wv * 16 + ln] = r[rr];
      }
      __syncthreads();
      {  // pointwise 2: inner cell + outputs; next outer c := hi_n
        float i2 = Clds[pb * C_ST + 0 * 16 + pj] + biv[0];
        float f2 = Clds[pb * C_ST + 1 * 16 + pj] + biv[1];
        float o2 = Clds[pb * C_ST + 2 * 16 + pj] + biv[2];
        float c2 = Clds[pb * C_ST + 3 * 16 + pj] + biv[3];
        float ci_n = sigf(f2) * st_ci + sigf(i2) * tanhf_(c2);
        float hi_n = sigf(o2) * tanhf_(ci_n);
        float h_n  = sigf(o_pre) * tanhf_(hi_n);
        st_ci = ci_n;
        st_c  = hi_n;  // reference: carry c <- hi_n
        hibuf[(size_t)((t + 1) & 1) * B_DIM * H_DIM + (size_t)brow * H_DIM + jglob] =
            (_Float16)hi_n;  // write parity
        hbuf[(size_t)brow * H_DIM + jglob] = (_Float16)h_n;
        out[((size_t)t * B_DIM + brow) * H_DIM + jglob] = h_n;  // l0: y0, l1: final
      }
      gbar(cnt, 32u * (++bseq));  // h/hi visible for next step
    }
  }
}

extern "C" void kernel_launch(void* const* d_in, const int* in_sizes, int n_in,
                              void* d_out, int out_size, void* d_ws, size_t ws_size,
                              hipStream_t stream) {
  const float* xin = (const float*)d_in[0];
  const float* h0  = (const float*)d_in[1];
  const float* Wg  = (const float*)d_in[2];
  const float* bg  = (const float*)d_in[3];
  const float* Wi  = (const float*)d_in[4];
  const float* bi  = (const float*)d_in[5];
  float* out = (float*)d_out;

  // ws layout: [0,4096) barrier counters; hbuf fp16 [B,H]; hibuf fp16 [2,B,H]
  // (t-parity ping-pong); cellbuf fp16 [B,H]. Total ~516 KiB.
  unsigned* bar   = (unsigned*)d_ws;
  _Float16* hbuf  = (_Float16*)((char*)d_ws + 4096);
  _Float16* hibuf = hbuf + (size_t)B_DIM * H_DIM;
  _Float16* cellb = hibuf + (size_t)2 * B_DIM * H_DIM;

  hipMemsetAsync(d_ws, 0, 4096, stream);  // barrier counters must start at 0

  nlstm_pers<<<dim3(256), dim3(256), 0, stream>>>(
      xin, h0, Wg, bg, Wi, bi, out, bar, hbuf, hibuf, cellb);
}

// Round 3
// 4048.497 us; speedup vs baseline: 3.1790x; 3.1790x over previous
//
#include <hip/hip_runtime.h>

#define T_DIM 256
#define B_DIM 128
#define C_DIM 512
#define H_DIM 512

typedef _Float16 half8 __attribute__((ext_vector_type(8)));
typedef float f32x4 __attribute__((ext_vector_type(4)));

// LDS: A-tile 32 ksteps x 16 rows x 80B (pad 64->80) = 40960 B
//      C-tile 16 x 65 floats = 4160 B
#define A_KS 640   // halfs per kstep
#define A_RS 40    // halfs per row
#define C_ST 65    // floats per row

__device__ __forceinline__ float sigf(float x) { return 1.0f / (1.0f + __expf(-x)); }
__device__ __forceinline__ float tanhf_(float x) {
  float e = __expf(2.0f * x);
  return (e - 1.0f) / (e + 1.0f);
}

__device__ __forceinline__ half8 cvt8(float4 a, float4 b) {
  half8 h;
  h[0] = (_Float16)a.x; h[1] = (_Float16)a.y; h[2] = (_Float16)a.z; h[3] = (_Float16)a.w;
  h[4] = (_Float16)b.x; h[5] = (_Float16)b.y; h[6] = (_Float16)b.z; h[7] = (_Float16)b.w;
  return h;
}

// XCD-local group barrier (32 blocks). Protocol:
//  - producers' plain stores are in L2 when they pass the first __syncthreads
//    (CDNA L1 is write-through; __syncthreads drains vmcnt(0) per wave).
//  - flag: RELAXED agent-scope RMW/poll -> no buffer_wbl2/inv_sc1 cache
//    maintenance is emitted (that full-L2 flush was the 12.5us/phase cost of
//    the previous acq/rel version). Flag correctness does not depend on XCD
//    placement (coherence-point RMW).
//  - consumer freshness: invalidate vector L1 only (buffer_inv sc0) and read
//    group-mates' data from the shared per-XCD L2. DATA freshness relies on
//    group (blockIdx&7) == XCD (round-robin dispatch); a violated assumption
//    fails loudly via absmax, not silently.
__device__ __forceinline__ void gbar(unsigned* cnt, unsigned target) {
  __syncthreads();  // all block stores drained to L2
  if (threadIdx.x == 0) {
    __hip_atomic_fetch_add(cnt, 1u, __ATOMIC_RELAXED, __HIP_MEMORY_SCOPE_AGENT);
    long long t0 = wall_clock64();
    while (__hip_atomic_load(cnt, __ATOMIC_RELAXED, __HIP_MEMORY_SCOPE_AGENT) < target) {
      __builtin_amdgcn_s_sleep(2);
      if (wall_clock64() - t0 > 1000000LL) break;  // ~10ms @100MHz anti-hang
    }
  }
  __syncthreads();
  asm volatile("buffer_inv sc0" ::: "memory");      // drop stale L1 lines
  asm volatile("s_waitcnt vmcnt(0)" ::: "memory");  // inv complete before loads
}

// Persistent nested-LSTM. Grid 256 blocks x 256 threads, 1 block/CU.
// 8 groups (blockIdx&7 = XCD) of 32 blocks; group g owns batch rows
// [16g,16g+16). Block bc=blockIdx>>3 owns gate cols j' in [16bc,16bc+16) ->
// 64 gate rows (4 gates x 16 j'); weights live in VGPRs as fp16 B-frags
// (256 regs/lane). Wave w computes gate w. Layer-0 h goes to d_out (fp32),
// read back as layer-1 input, then overwritten by layer-1 h. States c,ci fp32
// in regs of thread (b=tid&15, j'=tid>>4). Reference carry: next c = hi_n.
// hibuf ping-pongs on t-parity. Staging is software-pipelined: x-part of t+1
// is staged before the h-barrier; hi-part of phase 2 before the cell-barrier.
__global__ __launch_bounds__(256, 1) void nlstm_pers(
    const float* __restrict__ xin, const float* __restrict__ h0,
    const float* __restrict__ Wg, const float* __restrict__ bgb,
    const float* __restrict__ Wi, const float* __restrict__ bib,
    float* __restrict__ out, unsigned* __restrict__ bar,
    _Float16* __restrict__ hbuf, _Float16* __restrict__ hibuf,
    _Float16* __restrict__ cellbuf)
{
  __shared__ __align__(16) char smem[45120];
  _Float16* Alds = (_Float16*)smem;
  float* Clds = (float*)(smem + 40960);

  const int tid  = threadIdx.x;
  const int grp  = blockIdx.x & 7;
  const int bc   = blockIdx.x >> 3;
  const int wv   = tid >> 6;       // wave = gate index q
  const int lane = tid & 63;
  const int ln   = lane & 15;      // MFMA n / m lane index
  const int kg   = lane >> 4;      // MFMA k-group
  const int srow = lane >> 2;      // staging row 0..15
  const int squd = lane & 3;       // staging quad 0..3
  const int pb   = tid & 15;       // pointwise batch row (in group)
  const int pj   = tid >> 4;       // pointwise j' local 0..15
  const int brow = grp * 16 + pb;  // global batch row
  const int jglob = bc * 16 + pj;  // global j' 0..511
  const int ncol  = bc * 16 + ln;  // weight column for this lane

  unsigned* cnt = bar + grp * 32;
  unsigned bseq = 0;

  half8 wgf[32], wif[32];
  float st_c = 0.f, st_ci = 0.f, o_pre = 0.f;
  float bgv[4], biv[4];

  for (int l = 0; l < 2; ++l) {
    // ---- layer init: weights -> VGPR fp16 frags ----
    const float* wgrow = Wg + ((size_t)l * 2048 + wv * 512 + ncol) * 1024;
    const float* wirow = Wi + ((size_t)l * 2048 + wv * 512 + ncol) * 1024;
#pragma unroll
    for (int ks = 0; ks < 32; ++ks) {
      const float* p = wgrow + ks * 32 + kg * 8;
      wgf[ks] = cvt8(*(const float4*)p, *(const float4*)(p + 4));
      const float* q = wirow + ks * 32 + kg * 8;
      wif[ks] = cvt8(*(const float4*)q, *(const float4*)(q + 4));
    }
#pragma unroll
    for (int q = 0; q < 4; ++q) {
      bgv[q] = bgb[l * 2048 + q * 512 + jglob];
      biv[q] = bib[l * 2048 + q * 512 + jglob];
    }
    // states: h0[l] layout (h, c, h_inner, c_inner) each [B,H]
    const float* h0l = h0 + (size_t)l * 4 * B_DIM * H_DIM + (size_t)brow * H_DIM + jglob;
    float h_in  = h0l[0];
    st_c        = h0l[(size_t)1 * B_DIM * H_DIM];
    float hi_in = h0l[(size_t)2 * B_DIM * H_DIM];
    st_ci       = h0l[(size_t)3 * B_DIM * H_DIM];
    hbuf [(size_t)brow * H_DIM + jglob] = (_Float16)h_in;
    hibuf[(size_t)brow * H_DIM + jglob] = (_Float16)hi_in;  // t=0 reads parity 0
    gbar(cnt, 32u * (++bseq));

    // prestage x-part (ks 0..15) for t=0
    {
#pragma unroll
      for (int i = 0; i < 4; ++i) {
        const int ks = wv * 4 + i;
        const int col = ks * 32 + squd * 8;
        _Float16* dst = Alds + ks * A_KS + srow * A_RS + squd * 8;
        const float* p = (l == 0)
            ? xin + ((size_t)0 * B_DIM + grp * 16 + srow) * C_DIM + col
            : out + ((size_t)0 * B_DIM + grp * 16 + srow) * H_DIM + col;
        *(half8*)dst = cvt8(*(const float4*)p, *(const float4*)(p + 4));
      }
    }

    for (int t = 0; t < T_DIM; ++t) {
      // ---- stage h-part (ks 16..31) ----
      {
#pragma unroll
        for (int i = 0; i < 4; ++i) {
          const int ks = 16 + wv * 4 + i;
          const int col = (ks - 16) * 32 + squd * 8;
          _Float16* dst = Alds + ks * A_KS + srow * A_RS + squd * 8;
          const _Float16* p = hbuf + (size_t)(grp * 16 + srow) * H_DIM + col;
          *(uint4*)dst = *(const uint4*)p;
        }
      }
      __syncthreads();
      {  // ---- MFMA 1: g = [x_t | h] @ Wg^T ----
        f32x4 acc[4];
#pragma unroll
        for (int i = 0; i < 4; ++i) acc[i] = (f32x4){0.f, 0.f, 0.f, 0.f};
#pragma unroll
        for (int ks = 0; ks < 32; ++ks) {
          half8 a = *(const half8*)(Alds + ks * A_KS + ln * A_RS + kg * 8);
          acc[ks & 3] = __builtin_amdgcn_mfma_f32_16x16x32_f16(a, wgf[ks], acc[ks & 3], 0, 0, 0);
        }
        f32x4 r = acc[0] + acc[1] + acc[2] + acc[3];
#pragma unroll
        for (int rr = 0; rr < 4; ++rr)
          Clds[(kg * 4 + rr) * C_ST + wv * 16 + ln] = r[rr];
      }
      __syncthreads();
      {  // ---- prestage hi-part (ks 16..31) for phase 2 (mfma1 done with Alds) ----
        const _Float16* hird = hibuf + (size_t)(t & 1) * B_DIM * H_DIM;
#pragma unroll
        for (int i = 0; i < 4; ++i) {
          const int ks = 16 + wv * 4 + i;
          const int col = (ks - 16) * 32 + squd * 8;
          _Float16* dst = Alds + ks * A_KS + srow * A_RS + squd * 8;
          *(uint4*)dst = *(const uint4*)(hird + (size_t)(grp * 16 + srow) * H_DIM + col);
        }
      }
      {  // ---- pointwise 1: cell = sig(f)*c + sig(i)*tanh(gc); stash o ----
        float gi = Clds[pb * C_ST + 0 * 16 + pj] + bgv[0];
        float gf = Clds[pb * C_ST + 1 * 16 + pj] + bgv[1];
        float go = Clds[pb * C_ST + 2 * 16 + pj] + bgv[2];
        float gc = Clds[pb * C_ST + 3 * 16 + pj] + bgv[3];
        float cell = sigf(gf) * st_c + sigf(gi) * tanhf_(gc);
        o_pre = go;
        cellbuf[(size_t)brow * H_DIM + jglob] = (_Float16)cell;
      }
      gbar(cnt, 32u * (++bseq));  // cell visible group-wide

      // ---- stage cell-part (ks 0..15) ----
      {
#pragma unroll
        for (int i = 0; i < 4; ++i) {
          const int ks = wv * 4 + i;
          const int col = ks * 32 + squd * 8;
          _Float16* dst = Alds + ks * A_KS + srow * A_RS + squd * 8;
          *(uint4*)dst = *(const uint4*)(cellbuf + (size_t)(grp * 16 + srow) * H_DIM + col);
        }
      }
      __syncthreads();
      {  // ---- MFMA 2: g2 = [cell | hi] @ Wi^T ----
        f32x4 acc[4];
#pragma unroll
        for (int i = 0; i < 4; ++i) acc[i] = (f32x4){0.f, 0.f, 0.f, 0.f};
#pragma unroll
        for (int ks = 0; ks < 32; ++ks) {
          half8 a = *(const half8*)(Alds + ks * A_KS + ln * A_RS + kg * 8);
          acc[ks & 3] = __builtin_amdgcn_mfma_f32_16x16x32_f16(a, wif[ks], acc[ks & 3], 0, 0, 0);
        }
        f32x4 r = acc[0] + acc[1] + acc[2] + acc[3];
#pragma unroll
        for (int rr = 0; rr < 4; ++rr)
          Clds[(kg * 4 + rr) * C_ST + wv * 16 + ln] = r[rr];
      }
      __syncthreads();
      if (t + 1 < T_DIM) {  // ---- prestage x-part of t+1 (mfma2 done with Alds) ----
#pragma unroll
        for (int i = 0; i < 4; ++i) {
          const int ks = wv * 4 + i;
          const int col = ks * 32 + squd * 8;
          _Float16* dst = Alds + ks * A_KS + srow * A_RS + squd * 8;
          const float* p = (l == 0)
              ? xin + ((size_t)(t + 1) * B_DIM + grp * 16 + srow) * C_DIM + col
              : out + ((size_t)(t + 1) * B_DIM + grp * 16 + srow) * H_DIM + col;
          *(half8*)dst = cvt8(*(const float4*)p, *(const float4*)(p + 4));
        }
      }
      {  // ---- pointwise 2: inner cell + outputs; next outer c := hi_n ----
        float i2 = Clds[pb * C_ST + 0 * 16 + pj] + biv[0];
        float f2 = Clds[pb * C_ST + 1 * 16 + pj] + biv[1];
        float o2 = Clds[pb * C_ST + 2 * 16 + pj] + biv[2];
        float c2 = Clds[pb * C_ST + 3 * 16 + pj] + biv[3];
        float ci_n = sigf(f2) * st_ci + sigf(i2) * tanhf_(c2);
        float hi_n = sigf(o2) * tanhf_(ci_n);
        float h_n  = sigf(o_pre) * tanhf_(hi_n);
        st_ci = ci_n;
        st_c  = hi_n;  // reference: carry c <- hi_n
        hibuf[(size_t)((t + 1) & 1) * B_DIM * H_DIM + (size_t)brow * H_DIM + jglob] =
            (_Float16)hi_n;
        hbuf[(size_t)brow * H_DIM + jglob] = (_Float16)h_n;
        out[((size_t)t * B_DIM + brow) * H_DIM + jglob] = h_n;  // l0: y0, l1: final
      }
      gbar(cnt, 32u * (++bseq));  // h/hi visible for next step
    }
  }
}

extern "C" void kernel_launch(void* const* d_in, const int* in_sizes, int n_in,
                              void* d_out, int out_size, void* d_ws, size_t ws_size,
                              hipStream_t stream) {
  const float* xin = (const float*)d_in[0];
  const float* h0  = (const float*)d_in[1];
  const float* Wg  = (const float*)d_in[2];
  const float* bg  = (const float*)d_in[3];
  const float* Wi  = (const float*)d_in[4];
  const float* bi  = (const float*)d_in[5];
  float* out = (float*)d_out;

  // ws layout: [0,4096) barrier counters; hbuf fp16 [B,H]; hibuf fp16 [2,B,H]
  // (t-parity ping-pong); cellbuf fp16 [B,H]. Total ~516 KiB.
  unsigned* bar   = (unsigned*)d_ws;
  _Float16* hbuf  = (_Float16*)((char*)d_ws + 4096);
  _Float16* hibuf = hbuf + (size_t)B_DIM * H_DIM;
  _Float16* cellb = hibuf + (size_t)2 * B_DIM * H_DIM;

  hipMemsetAsync(d_ws, 0, 4096, stream);  // barrier counters must start at 0

  nlstm_pers<<<dim3(256), dim3(256), 0, stream>>>(
      xin, h0, Wg, bg, Wi, bi, out, bar, hbuf, hibuf, cellb);
}

// Round 4
// 3946.288 us; speedup vs baseline: 3.2613x; 1.0259x over previous
//
#include <hip/hip_runtime.h>

#define T_DIM 256
#define B_DIM 128
#define C_DIM 512
#define H_DIM 512

typedef _Float16 half8 __attribute__((ext_vector_type(8)));
typedef float f32x4 __attribute__((ext_vector_type(4)));

// LDS: A-tile 32 ksteps x 16 rows x 80B (pad 64->80) = 40960 B
//      C-tile 16 x 65 floats = 4160 B
#define A_KS 640   // halfs per kstep
#define A_RS 40    // halfs per row
#define C_ST 65    // floats per row

__device__ __forceinline__ float sigf(float x) { return 1.0f / (1.0f + __expf(-x)); }
__device__ __forceinline__ float tanhf_(float x) {
  float e = __expf(2.0f * x);
  return (e - 1.0f) / (e + 1.0f);
}

__device__ __forceinline__ half8 cvt8(float4 a, float4 b) {
  half8 h;
  h[0] = (_Float16)a.x; h[1] = (_Float16)a.y; h[2] = (_Float16)a.z; h[3] = (_Float16)a.w;
  h[4] = (_Float16)b.x; h[5] = (_Float16)b.y; h[6] = (_Float16)b.z; h[7] = (_Float16)b.w;
  return h;
}

// XCD-local group barrier (32 blocks), contention-free epoch protocol.
//  - R3's single-counter atomic RMW serialized 32 blocks at the coherence
//    point (~3-4k cy/phase). Now: block bc relax-stores epoch to its OWN slot
//    (32 slots = one 128B line per group) -> stores absorb in parallel.
//  - wave 0 polls all 32 slots with 32 lanes + one ballot -> detection is a
//    single load round-trip after the last arrival.
//  - data visibility: producers' plain stores are in L2 before the flag store
//    (L1 write-through; __syncthreads drains each thread's vmcnt). Consumers
//    drop stale L1 lines with buffer_inv sc0 and hit shared per-XCD L2.
//    Group (blockIdx&7) == XCD relies on round-robin dispatch; a violated
//    assumption fails loudly via absmax, not silently.
__device__ __forceinline__ void gbar(unsigned* slots, int bc, unsigned epoch) {
  __syncthreads();  // all block stores drained to L2
  if (threadIdx.x < 64) {
    if (threadIdx.x == 0)
      __hip_atomic_store(slots + bc, epoch, __ATOMIC_RELAXED, __HIP_MEMORY_SCOPE_AGENT);
    const int lane = threadIdx.x;
    long long t0 = wall_clock64();
    for (;;) {
      unsigned v = (lane < 32)
          ? __hip_atomic_load(slots + lane, __ATOMIC_RELAXED, __HIP_MEMORY_SCOPE_AGENT)
          : epoch;
      if (__ballot(v >= epoch) == ~0ull) break;
      if (wall_clock64() - t0 > 1000000LL) break;  // ~10ms @100MHz anti-hang
    }
  }
  __syncthreads();
  asm volatile("buffer_inv sc0" ::: "memory");      // drop stale L1 lines
  asm volatile("s_waitcnt vmcnt(0)" ::: "memory");  // inv complete before loads
}

// Persistent nested-LSTM. Grid 256 blocks x 256 threads, 1 block/CU.
// 8 groups (blockIdx&7 = XCD) of 32 blocks; group g owns batch rows
// [16g,16g+16). Block bc=blockIdx>>3 owns gate cols j' in [16bc,16bc+16) ->
// 64 gate rows (4 gates x 16 j'); weights live in VGPRs as fp16 B-frags
// (256 regs/lane). Wave w computes gate w. Layer-0 h goes to d_out (fp32),
// read back as layer-1 input, then overwritten by layer-1 h. States c,ci fp32
// in regs of thread (b=tid>>4, j'=tid&15 -> 16 consecutive-j' lanes give
// coalesced exchange stores). Reference carry: next c = hi_n.
// hibuf ping-pongs on t-parity. Staging software-pipelined: x(t+1) staged
// before the h-barrier; hi-part of phase 2 before the cell-barrier.
__global__ __launch_bounds__(256, 1) void nlstm_pers(
    const float* __restrict__ xin, const float* __restrict__ h0,
    const float* __restrict__ Wg, const float* __restrict__ bgb,
    const float* __restrict__ Wi, const float* __restrict__ bib,
    float* __restrict__ out, unsigned* __restrict__ bar,
    _Float16* __restrict__ hbuf, _Float16* __restrict__ hibuf,
    _Float16* __restrict__ cellbuf)
{
  __shared__ __align__(16) char smem[45120];
  _Float16* Alds = (_Float16*)smem;
  float* Clds = (float*)(smem + 40960);

  const int tid  = threadIdx.x;
  const int grp  = blockIdx.x & 7;
  const int bc   = blockIdx.x >> 3;
  const int wv   = tid >> 6;       // wave = gate index q
  const int lane = tid & 63;
  const int ln   = lane & 15;      // MFMA n / m lane index
  const int kg   = lane >> 4;      // MFMA k-group
  const int srow = lane >> 2;      // staging row 0..15
  const int squd = lane & 3;       // staging quad 0..3
  const int pb   = tid >> 4;       // pointwise batch row (in group) 0..15
  const int pj   = tid & 15;       // pointwise j' local 0..15 (lane-consecutive)
  const int brow = grp * 16 + pb;  // global batch row
  const int jglob = bc * 16 + pj;  // global j' 0..511
  const int ncol  = bc * 16 + ln;  // weight column for this lane

  unsigned* slots = bar + grp * 64;  // 32 used, 256B stride between groups
  unsigned bseq = 0;

  half8 wgf[32], wif[32];
  float st_c = 0.f, st_ci = 0.f, o_pre = 0.f;
  float bgv[4], biv[4];

  for (int l = 0; l < 2; ++l) {
    // ---- layer init: weights -> VGPR fp16 frags ----
    const float* wgrow = Wg + ((size_t)l * 2048 + wv * 512 + ncol) * 1024;
    const float* wirow = Wi + ((size_t)l * 2048 + wv * 512 + ncol) * 1024;
#pragma unroll
    for (int ks = 0; ks < 32; ++ks) {
      const float* p = wgrow + ks * 32 + kg * 8;
      wgf[ks] = cvt8(*(const float4*)p, *(const float4*)(p + 4));
      const float* q = wirow + ks * 32 + kg * 8;
      wif[ks] = cvt8(*(const float4*)q, *(const float4*)(q + 4));
    }
#pragma unroll
    for (int q = 0; q < 4; ++q) {
      bgv[q] = bgb[l * 2048 + q * 512 + jglob];
      biv[q] = bib[l * 2048 + q * 512 + jglob];
    }
    // states: h0[l] layout (h, c, h_inner, c_inner) each [B,H]
    const float* h0l = h0 + (size_t)l * 4 * B_DIM * H_DIM + (size_t)brow * H_DIM + jglob;
    float h_in  = h0l[0];
    st_c        = h0l[(size_t)1 * B_DIM * H_DIM];
    float hi_in = h0l[(size_t)2 * B_DIM * H_DIM];
    st_ci       = h0l[(size_t)3 * B_DIM * H_DIM];
    hbuf [(size_t)brow * H_DIM + jglob] = (_Float16)h_in;
    hibuf[(size_t)brow * H_DIM + jglob] = (_Float16)hi_in;  // t=0 reads parity 0
    gbar(slots, bc, ++bseq);

    // prestage x-part (ks 0..15) for t=0
    {
#pragma unroll
      for (int i = 0; i < 4; ++i) {
        const int ks = wv * 4 + i;
        const int col = ks * 32 + squd * 8;
        _Float16* dst = Alds + ks * A_KS + srow * A_RS + squd * 8;
        const float* p = (l == 0)
            ? xin + ((size_t)0 * B_DIM + grp * 16 + srow) * C_DIM + col
            : out + ((size_t)0 * B_DIM + grp * 16 + srow) * H_DIM + col;
        *(half8*)dst = cvt8(*(const float4*)p, *(const float4*)(p + 4));
      }
    }

    for (int t = 0; t < T_DIM; ++t) {
      // ---- stage h-part (ks 16..31) ----
      {
#pragma unroll
        for (int i = 0; i < 4; ++i) {
          const int ks = 16 + wv * 4 + i;
          const int col = (ks - 16) * 32 + squd * 8;
          _Float16* dst = Alds + ks * A_KS + srow * A_RS + squd * 8;
          const _Float16* p = hbuf + (size_t)(grp * 16 + srow) * H_DIM + col;
          *(uint4*)dst = *(const uint4*)p;
        }
      }
      __syncthreads();
      {  // ---- MFMA 1: g = [x_t | h] @ Wg^T ----
        f32x4 acc[4];
#pragma unroll
        for (int i = 0; i < 4; ++i) acc[i] = (f32x4){0.f, 0.f, 0.f, 0.f};
#pragma unroll
        for (int ks = 0; ks < 32; ++ks) {
          half8 a = *(const half8*)(Alds + ks * A_KS + ln * A_RS + kg * 8);
          acc[ks & 3] = __builtin_amdgcn_mfma_f32_16x16x32_f16(a, wgf[ks], acc[ks & 3], 0, 0, 0);
        }
        f32x4 r = acc[0] + acc[1] + acc[2] + acc[3];
#pragma unroll
        for (int rr = 0; rr < 4; ++rr)
          Clds[(kg * 4 + rr) * C_ST + wv * 16 + ln] = r[rr];
      }
      __syncthreads();
      {  // ---- prestage hi-part (ks 16..31) for phase 2 (mfma1 done with Alds) ----
        const _Float16* hird = hibuf + (size_t)(t & 1) * B_DIM * H_DIM;
#pragma unroll
        for (int i = 0; i < 4; ++i) {
          const int ks = 16 + wv * 4 + i;
          const int col = (ks - 16) * 32 + squd * 8;
          _Float16* dst = Alds + ks * A_KS + srow * A_RS + squd * 8;
          *(uint4*)dst = *(const uint4*)(hird + (size_t)(grp * 16 + srow) * H_DIM + col);
        }
      }
      {  // ---- pointwise 1: cell = sig(f)*c + sig(i)*tanh(gc); stash o ----
        float gi = Clds[pb * C_ST + 0 * 16 + pj] + bgv[0];
        float gf = Clds[pb * C_ST + 1 * 16 + pj] + bgv[1];
        float go = Clds[pb * C_ST + 2 * 16 + pj] + bgv[2];
        float gc = Clds[pb * C_ST + 3 * 16 + pj] + bgv[3];
        float cell = sigf(gf) * st_c + sigf(gi) * tanhf_(gc);
        o_pre = go;
        cellbuf[(size_t)brow * H_DIM + jglob] = (_Float16)cell;
      }
      gbar(slots, bc, ++bseq);  // cell visible group-wide

      // ---- stage cell-part (ks 0..15) ----
      {
#pragma unroll
        for (int i = 0; i < 4; ++i) {
          const int ks = wv * 4 + i;
          const int col = ks * 32 + squd * 8;
          _Float16* dst = Alds + ks * A_KS + srow * A_RS + squd * 8;
          *(uint4*)dst = *(const uint4*)(cellbuf + (size_t)(grp * 16 + srow) * H_DIM + col);
        }
      }
      __syncthreads();
      {  // ---- MFMA 2: g2 = [cell | hi] @ Wi^T ----
        f32x4 acc[4];
#pragma unroll
        for (int i = 0; i < 4; ++i) acc[i] = (f32x4){0.f, 0.f, 0.f, 0.f};
#pragma unroll
        for (int ks = 0; ks < 32; ++ks) {
          half8 a = *(const half8*)(Alds + ks * A_KS + ln * A_RS + kg * 8);
          acc[ks & 3] = __builtin_amdgcn_mfma_f32_16x16x32_f16(a, wif[ks], acc[ks & 3], 0, 0, 0);
        }
        f32x4 r = acc[0] + acc[1] + acc[2] + acc[3];
#pragma unroll
        for (int rr = 0; rr < 4; ++rr)
          Clds[(kg * 4 + rr) * C_ST + wv * 16 + ln] = r[rr];
      }
      __syncthreads();
      if (t + 1 < T_DIM) {  // ---- prestage x-part of t+1 (mfma2 done with Alds) ----
#pragma unroll
        for (int i = 0; i < 4; ++i) {
          const int ks = wv * 4 + i;
          const int col = ks * 32 + squd * 8;
          _Float16* dst = Alds + ks * A_KS + srow * A_RS + squd * 8;
          const float* p = (l == 0)
              ? xin + ((size_t)(t + 1) * B_DIM + grp * 16 + srow) * C_DIM + col
              : out + ((size_t)(t + 1) * B_DIM + grp * 16 + srow) * H_DIM + col;
          *(half8*)dst = cvt8(*(const float4*)p, *(const float4*)(p + 4));
        }
      }
      {  // ---- pointwise 2: inner cell + outputs; next outer c := hi_n ----
        float i2 = Clds[pb * C_ST + 0 * 16 + pj] + biv[0];
        float f2 = Clds[pb * C_ST + 1 * 16 + pj] + biv[1];
        float o2 = Clds[pb * C_ST + 2 * 16 + pj] + biv[2];
        float c2 = Clds[pb * C_ST + 3 * 16 + pj] + biv[3];
        float ci_n = sigf(f2) * st_ci + sigf(i2) * tanhf_(c2);
        float hi_n = sigf(o2) * tanhf_(ci_n);
        float h_n  = sigf(o_pre) * tanhf_(hi_n);
        st_ci = ci_n;
        st_c  = hi_n;  // reference: carry c <- hi_n
        hibuf[(size_t)((t + 1) & 1) * B_DIM * H_DIM + (size_t)brow * H_DIM + jglob] =
            (_Float16)hi_n;
        hbuf[(size_t)brow * H_DIM + jglob] = (_Float16)h_n;
        out[((size_t)t * B_DIM + brow) * H_DIM + jglob] = h_n;  // l0: y0, l1: final
      }
      gbar(slots, bc, ++bseq);  // h/hi visible for next step
    }
  }
}

extern "C" void kernel_launch(void* const* d_in, const int* in_sizes, int n_in,
                              void* d_out, int out_size, void* d_ws, size_t ws_size,
                              hipStream_t stream) {
  const float* xin = (const float*)d_in[0];
  const float* h0  = (const float*)d_in[1];
  const float* Wg  = (const float*)d_in[2];
  const float* bg  = (const float*)d_in[3];
  const float* Wi  = (const float*)d_in[4];
  const float* bi  = (const float*)d_in[5];
  float* out = (float*)d_out;

  // ws layout: [0,4096) barrier epoch slots (8 groups x 256B); hbuf fp16 [B,H];
  // hibuf fp16 [2,B,H] (t-parity ping-pong); cellbuf fp16 [B,H]. ~516 KiB.
  unsigned* bar   = (unsigned*)d_ws;
  _Float16* hbuf  = (_Float16*)((char*)d_ws + 4096);
  _Float16* hibuf = hbuf + (size_t)B_DIM * H_DIM;
  _Float16* cellb = hibuf + (size_t)2 * B_DIM * H_DIM;

  hipMemsetAsync(d_ws, 0, 4096, stream);  // epoch slots must start at 0

  nlstm_pers<<<dim3(256), dim3(256), 0, stream>>>(
      xin, h0, Wg, bg, Wi, bi, out, bar, hbuf, hibuf, cellb);
}

// Round 6
// 3875.214 us; speedup vs baseline: 3.3211x; 1.0183x over previous
//
#include <hip/hip_runtime.h>

#define T_DIM 256
#define B_DIM 128
#define C_DIM 512
#define H_DIM 512

typedef _Float16 half8 __attribute__((ext_vector_type(8)));
typedef float f32x4 __attribute__((ext_vector_type(4)));

__device__ __forceinline__ float sigf(float x) { return 1.0f / (1.0f + __expf(-x)); }
__device__ __forceinline__ float tanhf_(float x) {
  float e = __expf(2.0f * x);
  return (e - 1.0f) / (e + 1.0f);
}

__device__ __forceinline__ half8 cvt8(float4 a, float4 b) {
  half8 h;
  h[0] = (_Float16)a.x; h[1] = (_Float16)a.y; h[2] = (_Float16)a.z; h[3] = (_Float16)a.w;
  h[4] = (_Float16)b.x; h[5] = (_Float16)b.y; h[6] = (_Float16)b.z; h[7] = (_Float16)b.w;
  return h;
}

// XCD-local group barrier (32 blocks), epoch slots. R4-PROVEN flag protocol:
// agent-scope RELAXED atomic store (arrive) + agent-scope RELAXED atomic load
// (poll). R5's sc0-asm poll read stale L1 forever (every barrier timed out) —
// do not substitute unproven cache-bit semantics here.
//  - producer data: plain stores are in the XCD L2 when the wave passes
//    __syncthreads (L1 write-through + vmcnt(0) drain).
//  - wave 0 polls the 32 slots with lanes (2 lanes/slot) + one ballot.
//  - consumer data freshness: buffer_inv sc0 drops stale L1 lines; reads then
//    hit the shared per-XCD L2. Relies on group(blockIdx&7)==XCD (round-robin
//    dispatch); violation fails loudly via absmax, not silently.
__device__ __forceinline__ void gbar(unsigned* slots, int bc, unsigned epoch) {
  __syncthreads();
  if (threadIdx.x < 64) {
    if (threadIdx.x == 0)
      __hip_atomic_store(slots + bc, epoch, __ATOMIC_RELAXED, __HIP_MEMORY_SCOPE_AGENT);
    const unsigned* myslot = slots + (threadIdx.x & 31);
    int guard = 0;
    for (;;) {
      unsigned v = __hip_atomic_load(myslot, __ATOMIC_RELAXED, __HIP_MEMORY_SCOPE_AGENT);
      if (__ballot(v >= epoch) == ~0ull) break;
      if (++guard > (1 << 15)) break;  // anti-hang: fail loud, not dead
    }
  }
  __syncthreads();
  asm volatile("buffer_inv sc0" ::: "memory");      // drop stale L1 lines
  asm volatile("s_waitcnt vmcnt(0)" ::: "memory");  // inv complete before loads
}

// Persistent nested-LSTM. Grid 256x256, 1 block/CU. 8 groups (blockIdx&7=XCD)
// x 32 blocks; group g owns batch rows [16g,16g+16); block bc owns gate cols
// [16bc,16bc+16).
// K-SPLIT: wave w holds fp16 B-frags of ALL 4 gates for K-slice
// [256w,256w+256) of both Wg,Wi (64 half8 = 256 VGPRs) -> each wave reads
// only 8KB of the A-tile (8 ds_read_b128), then 32 MFMA; per-gate f32x4
// partials reduced via 16KB LDS buffer directly by pointwise threads.
// FRAGMENT-LINEAR LDS A-tile: addr = ks*1024B + lane*16B -> zero-conflict
// ds_read_b128 (R4's 80B row stride was 8-way conflicted: 2.18e8 cycles).
// Exchange buffers (h/hi/cell) are stored in the same fragment order ->
// staging is a contiguous 16KB copy. Value (row m, col c) lives at half-offset
// (c>>5)*512 + (((c>>3)&3)*16+m)*8 + (c&7) within the group's 8192-half slab.
// States c,ci fp32 in regs of thread (pb=tid>>4, pj=tid&15). Reference
// carry: next outer c = hi_n. hibuf ping-pongs on t-parity.
__global__ __launch_bounds__(256, 1) void nlstm_pers(
    const float* __restrict__ xin, const float* __restrict__ h0,
    const float* __restrict__ Wg, const float* __restrict__ bgb,
    const float* __restrict__ Wi, const float* __restrict__ bib,
    float* __restrict__ out, unsigned* __restrict__ bar,
    _Float16* __restrict__ hbuf, _Float16* __restrict__ hibuf,
    _Float16* __restrict__ cellbuf)
{
  // LDS: A-tile 32ks x 1024B fragment-linear = 32KB; partials 4g*16*16*f32x4 = 16KB
  __shared__ __align__(16) char smem[49152];
  _Float16* AldsH = (_Float16*)smem;
  float* Pl = (float*)(smem + 32768);

  const int tid  = threadIdx.x;
  const int grp  = blockIdx.x & 7;
  const int bc   = blockIdx.x >> 3;
  const int wv   = tid >> 6;       // wave = K-slice owner
  const int lane = tid & 63;
  const int ln   = lane & 15;      // MFMA m/n lane index
  const int kg   = lane >> 4;      // MFMA k-subgroup
  const int pb   = tid >> 4;       // pointwise batch row (in group) 0..15
  const int pj   = tid & 15;       // pointwise j' local (lane-consecutive)
  const int brow = grp * 16 + pb;  // global batch row
  const int jglob = bc * 16 + pj;  // global j' 0..511
  const int ncol  = bc * 16 + ln;  // weight row (= output col) for this lane

  // fragment-order offset of (row=pb, col=jglob) in a group slab (halfs)
  const int exoff = (jglob >> 5) * 512 + (((jglob >> 3) & 3) * 16 + pb) * 8 + (jglob & 7);

  _Float16* hbase = hbuf + grp * 8192;
  _Float16* cbase = cellbuf + grp * 8192;

  unsigned* slots = bar + grp * 64;  // 32 used per group
  unsigned bseq = 0;

  half8 wgf[4][8], wif[4][8];
  float st_c = 0.f, st_ci = 0.f, o_pre = 0.f;
  float bgv[4], biv[4];

  for (int l = 0; l < 2; ++l) {
    // ---- layer init: weights -> VGPR fp16 frags (wave wv: K cols [256wv,256wv+256)) ----
#pragma unroll
    for (int g = 0; g < 4; ++g) {
      const float* wgr = Wg + ((size_t)l * 2048 + g * 512 + ncol) * 1024 + wv * 256;
      const float* wir = Wi + ((size_t)l * 2048 + g * 512 + ncol) * 1024 + wv * 256;
#pragma unroll
      for (int i = 0; i < 8; ++i) {
        const float* p = wgr + i * 32 + kg * 8;
        wgf[g][i] = cvt8(*(const float4*)p, *(const float4*)(p + 4));
        const float* q = wir + i * 32 + kg * 8;
        wif[g][i] = cvt8(*(const float4*)q, *(const float4*)(q + 4));
      }
      bgv[g] = bgb[l * 2048 + g * 512 + jglob];
      biv[g] = bib[l * 2048 + g * 512 + jglob];
    }
    // states: h0[l] layout (h, c, h_inner, c_inner) each [B,H]
    const float* h0l = h0 + (size_t)l * 4 * B_DIM * H_DIM + (size_t)brow * H_DIM + jglob;
    float h_in  = h0l[0];
    st_c        = h0l[(size_t)1 * B_DIM * H_DIM];
    float hi_in = h0l[(size_t)2 * B_DIM * H_DIM];
    st_ci       = h0l[(size_t)3 * B_DIM * H_DIM];
    hbase[exoff] = (_Float16)h_in;
    hibuf[grp * 8192 + exoff] = (_Float16)hi_in;  // parity 0 read at t=0
    gbar(slots, bc, ++bseq);

    // ---- prestage x(t=0) into Alds ks 0..15 ----
    {
      const int m   = tid & 15;
      const int kq  = (tid >> 4) & 3;
      const float* srow_p = (l == 0)
          ? xin + ((size_t)0 * B_DIM + grp * 16 + m) * C_DIM
          : out + ((size_t)0 * B_DIM + grp * 16 + m) * H_DIM;
#pragma unroll
      for (int i = 0; i < 4; ++i) {
        const int ks = wv + i * 4;
        const float* p = srow_p + ks * 32 + kq * 8;
        *(half8*)(AldsH + ks * 512 + (kq * 16 + m) * 8) =
            cvt8(*(const float4*)p, *(const float4*)(p + 4));
      }
    }

    for (int t = 0; t < T_DIM; ++t) {
      // ---- stage h -> Alds ks 16..31 (contiguous 16KB copy) ----
#pragma unroll
      for (int i = 0; i < 4; ++i) {
        const int idx = i * 256 + tid;
        *(uint4*)(AldsH + 8192 + idx * 8) = *(const uint4*)(hbase + idx * 8);
      }
      __syncthreads();
      {  // ---- MFMA 1: wave wv's K-slice of g = [x|h] @ Wg^T, all 4 gates ----
        f32x4 acc[4];
#pragma unroll
        for (int g = 0; g < 4; ++g) acc[g] = (f32x4){0.f, 0.f, 0.f, 0.f};
#pragma unroll
        for (int i = 0; i < 8; ++i) {
          half8 a = *(const half8*)(AldsH + (wv * 8 + i) * 512 + lane * 8);
#pragma unroll
          for (int g = 0; g < 4; ++g)
            acc[g] = __builtin_amdgcn_mfma_f32_16x16x32_f16(a, wgf[g][i], acc[g], 0, 0, 0);
        }
#pragma unroll
        for (int g = 0; g < 4; ++g)
#pragma unroll
          for (int rr = 0; rr < 4; ++rr)
            Pl[((g * 16 + kg * 4 + rr) * 16 + ln) * 4 + wv] = acc[g][rr];
      }
      __syncthreads();
      {  // ---- prestage hi -> Alds ks 16..31 (MFMA1 done with A) ----
        const _Float16* hird = hibuf + (size_t)(t & 1) * 65536 + grp * 8192;
#pragma unroll
        for (int i = 0; i < 4; ++i) {
          const int idx = i * 256 + tid;
          *(uint4*)(AldsH + 8192 + idx * 8) = *(const uint4*)(hird + idx * 8);
        }
      }
      {  // ---- pointwise 1: reduce 4 K-partials; cell = sig(f)*c + sig(i)*tanh(gc) ----
        f32x4 v0 = *(const f32x4*)(Pl + ((0 * 16 + pb) * 16 + pj) * 4);
        f32x4 v1 = *(const f32x4*)(Pl + ((1 * 16 + pb) * 16 + pj) * 4);
        f32x4 v2 = *(const f32x4*)(Pl + ((2 * 16 + pb) * 16 + pj) * 4);
        f32x4 v3 = *(const f32x4*)(Pl + ((3 * 16 + pb) * 16 + pj) * 4);
        float gi = v0[0] + v0[1] + v0[2] + v0[3] + bgv[0];
        float gf = v1[0] + v1[1] + v1[2] + v1[3] + bgv[1];
        float go = v2[0] + v2[1] + v2[2] + v2[3] + bgv[2];
        float gc = v3[0] + v3[1] + v3[2] + v3[3] + bgv[3];
        float cell = sigf(gf) * st_c + sigf(gi) * tanhf_(gc);
        o_pre = go;
        cbase[exoff] = (_Float16)cell;
      }
      gbar(slots, bc, ++bseq);  // cell visible group-wide

      // ---- stage cell -> Alds ks 0..15 (contiguous 16KB copy) ----
#pragma unroll
      for (int i = 0; i < 4; ++i) {
        const int idx = i * 256 + tid;
        *(uint4*)(AldsH + idx * 8) = *(const uint4*)(cbase + idx * 8);
      }
      __syncthreads();
      {  // ---- MFMA 2: wave wv's K-slice of g2 = [cell|hi] @ Wi^T ----
        f32x4 acc[4];
#pragma unroll
        for (int g = 0; g < 4; ++g) acc[g] = (f32x4){0.f, 0.f, 0.f, 0.f};
#pragma unroll
        for (int i = 0; i < 8; ++i) {
          half8 a = *(const half8*)(AldsH + (wv * 8 + i) * 512 + lane * 8);
#pragma unroll
          for (int g = 0; g < 4; ++g)
            acc[g] = __builtin_amdgcn_mfma_f32_16x16x32_f16(a, wif[g][i], acc[g], 0, 0, 0);
        }
#pragma unroll
        for (int g = 0; g < 4; ++g)
#pragma unroll
          for (int rr = 0; rr < 4; ++rr)
            Pl[((g * 16 + kg * 4 + rr) * 16 + ln) * 4 + wv] = acc[g][rr];
      }
      __syncthreads();
      if (t + 1 < T_DIM) {  // ---- prestage x(t+1) -> Alds ks 0..15 ----
        const int m   = tid & 15;
        const int kq  = (tid >> 4) & 3;
        const float* srow_p = (l == 0)
            ? xin + ((size_t)(t + 1) * B_DIM + grp * 16 + m) * C_DIM
            : out + ((size_t)(t + 1) * B_DIM + grp * 16 + m) * H_DIM;
#pragma unroll
        for (int i = 0; i < 4; ++i) {
          const int ks = wv + i * 4;
          const float* p = srow_p + ks * 32 + kq * 8;
          *(half8*)(AldsH + ks * 512 + (kq * 16 + m) * 8) =
              cvt8(*(const float4*)p, *(const float4*)(p + 4));
        }
      }
      {  // ---- pointwise 2: reduce partials; inner cell; outputs; c := hi_n ----
        f32x4 v0 = *(const f32x4*)(Pl + ((0 * 16 + pb) * 16 + pj) * 4);
        f32x4 v1 = *(const f32x4*)(Pl + ((1 * 16 + pb) * 16 + pj) * 4);
        f32x4 v2 = *(const f32x4*)(Pl + ((2 * 16 + pb) * 16 + pj) * 4);
        f32x4 v3 = *(const f32x4*)(Pl + ((3 * 16 + pb) * 16 + pj) * 4);
        float i2 = v0[0] + v0[1] + v0[2] + v0[3] + biv[0];
        float f2 = v1[0] + v1[1] + v1[2] + v1[3] + biv[1];
        float o2 = v2[0] + v2[1] + v2[2] + v2[3] + biv[2];
        float c2 = v3[0] + v3[1] + v3[2] + v3[3] + biv[3];
        float ci_n = sigf(f2) * st_ci + sigf(i2) * tanhf_(c2);
        float hi_n = sigf(o2) * tanhf_(ci_n);
        float h_n  = sigf(o_pre) * tanhf_(hi_n);
        st_ci = ci_n;
        st_c  = hi_n;  // reference: carry c <- hi_n
        hibuf[(size_t)((t + 1) & 1) * 65536 + grp * 8192 + exoff] = (_Float16)hi_n;
        hbase[exoff] = (_Float16)h_n;
        out[((size_t)t * B_DIM + brow) * H_DIM + jglob] = h_n;  // l0: y0, l1: final
      }
      gbar(slots, bc, ++bseq);  // h/hi visible for next step
    }
  }
}

extern "C" void kernel_launch(void* const* d_in, const int* in_sizes, int n_in,
                              void* d_out, int out_size, void* d_ws, size_t ws_size,
                              hipStream_t stream) {
  const float* xin = (const float*)d_in[0];
  const float* h0  = (const float*)d_in[1];
  const float* Wg  = (const float*)d_in[2];
  const float* bg  = (const float*)d_in[3];
  const float* Wi  = (const float*)d_in[4];
  const float* bi  = (const float*)d_in[5];
  float* out = (float*)d_out;

  // ws: [0,4KB) epoch slots (8 groups x 256B); hbuf fp16 [8][8192] (128KB);
  // hibuf fp16 [2][8][8192] (256KB); cellbuf fp16 [8][8192] (128KB). ~516KB.
  unsigned* bar   = (unsigned*)d_ws;
  _Float16* hbuf  = (_Float16*)((char*)d_ws + 4096);
  _Float16* hibuf = hbuf + (size_t)8 * 8192;
  _Float16* cellb = hibuf + (size_t)2 * 8 * 8192;

  hipMemsetAsync(d_ws, 0, 4096, stream);  // epoch slots must start at 0

  nlstm_pers<<<dim3(256), dim3(256), 0, stream>>>(
      xin, h0, Wg, bg, Wi, bi, out, bar, hbuf, hibuf, cellb);
}

// Round 7
// 3386.327 us; speedup vs baseline: 3.8006x; 1.1444x over previous
//
#include <hip/hip_runtime.h>

#define T_DIM 256
#define B_DIM 128
#define C_DIM 512
#define H_DIM 512

typedef _Float16 half8 __attribute__((ext_vector_type(8)));
typedef float f32x4 __attribute__((ext_vector_type(4)));

__device__ __forceinline__ float sigf(float x) { return 1.0f / (1.0f + __expf(-x)); }
__device__ __forceinline__ float tanhf_(float x) {
  float e = __expf(2.0f * x);
  return (e - 1.0f) / (e + 1.0f);
}

__device__ __forceinline__ half8 cvt8(float4 a, float4 b) {
  half8 h;
  h[0] = (_Float16)a.x; h[1] = (_Float16)a.y; h[2] = (_Float16)a.z; h[3] = (_Float16)a.w;
  h[4] = (_Float16)b.x; h[5] = (_Float16)b.y; h[6] = (_Float16)b.z; h[7] = (_Float16)b.w;
  return h;
}

// XCD-local group barrier (32 blocks), split into arrive/wait so independent
// staging work can overlap the poll window.
//  - arrive: __syncthreads drains ALL waves' data stores to L2 (L1 is
//    write-through), then tid0 plain-stores the epoch flag (posted to L2;
//    same-L2 ordering guarantees data-before-flag for group-mates).
//  - wait: wave0 polls the 32 slots (2 lanes/slot) with PLAIN volatile loads,
//    forcing an L1 miss each iteration via buffer_inv sc0 (the same inv+plain
//    -load combination the passing data path already relies on) -> poll
//    quantum is an XCD-L2 round trip, not an LLC one (R6's agent-scope loads).
//  - closing inv drops stale L1 lines before consumers read exchange data.
//  Relies on group(blockIdx&7)==XCD (round-robin dispatch); violation fails
//  loudly via absmax/timeout, not silently.
__device__ __forceinline__ void gbar_arrive(unsigned* slots, int bc, unsigned epoch) {
  __syncthreads();
  if (threadIdx.x == 0)
    *(volatile unsigned*)(slots + bc) = epoch;
}

__device__ __forceinline__ void gbar_wait(const unsigned* slots, unsigned epoch) {
  if (threadIdx.x < 64) {
    const volatile unsigned* myslot =
        (const volatile unsigned*)(slots + (threadIdx.x & 31));
    int guard = 0;
    for (;;) {
      asm volatile("buffer_inv sc0\n\ts_waitcnt vmcnt(0)" ::: "memory");
      unsigned v = *myslot;
      if (__ballot(v >= epoch) == ~0ull) break;
      if (++guard > (1 << 14)) break;  // anti-hang: fail loud, not dead
    }
  }
  __syncthreads();
  asm volatile("buffer_inv sc0" ::: "memory");      // drop stale L1 lines
  asm volatile("s_waitcnt vmcnt(0)" ::: "memory");  // inv complete before loads
}

// Persistent nested-LSTM. Grid 256x256, 1 block/CU. 8 groups (blockIdx&7=XCD)
// x 32 blocks; group g owns batch rows [16g,16g+16); block bc owns gate cols
// [16bc,16bc+16). K-SPLIT: wave w holds fp16 B-frags of all 4 gates for
// K-slice [256w,256w+256) of Wg,Wi (256 VGPRs); 8 ds_read_b128 + 32 MFMA per
// wave per GEMM; per-gate f32x4 partials reduced via LDS Pl buffer.
// Pl writes are slot-swizzled (wv^kg) to spread banks (was 8-way conflicted);
// reader sums all 4 slots so the permutation is invisible.
// FRAGMENT-LINEAR LDS A-tile: addr = ks*1024B + lane*16B, conflict-free.
// Exchange buffers (h/hi/cell) in fragment order; value (row m, col c) at
// half-offset (c>>5)*512 + (((c>>3)&3)*16+m)*8 + (c&7) in the group's slab.
// States c,ci fp32 in regs (pb=tid>>4, pj=tid&15). Reference carry: next
// outer c = hi_n. hibuf ping-pongs on t-parity. Prestages of hi and x(t+1)
// sit INSIDE the barrier poll windows.
__global__ __launch_bounds__(256, 1) void nlstm_pers(
    const float* __restrict__ xin, const float* __restrict__ h0,
    const float* __restrict__ Wg, const float* __restrict__ bgb,
    const float* __restrict__ Wi, const float* __restrict__ bib,
    float* __restrict__ out, unsigned* __restrict__ bar,
    _Float16* __restrict__ hbuf, _Float16* __restrict__ hibuf,
    _Float16* __restrict__ cellbuf)
{
  // LDS: A-tile 32ks x 1024B fragment-linear = 32KB; partials 16KB
  __shared__ __align__(16) char smem[49152];
  _Float16* AldsH = (_Float16*)smem;
  float* Pl = (float*)(smem + 32768);

  const int tid  = threadIdx.x;
  const int grp  = blockIdx.x & 7;
  const int bc   = blockIdx.x >> 3;
  const int wv   = tid >> 6;       // wave = K-slice owner
  const int lane = tid & 63;
  const int ln   = lane & 15;      // MFMA m/n lane index
  const int kg   = lane >> 4;      // MFMA k-subgroup
  const int pb   = tid >> 4;       // pointwise batch row (in group) 0..15
  const int pj   = tid & 15;       // pointwise j' local (lane-consecutive)
  const int brow = grp * 16 + pb;  // global batch row
  const int jglob = bc * 16 + pj;  // global j' 0..511
  const int ncol  = bc * 16 + ln;  // weight row (= output col) for this lane

  // fragment-order offset of (row=pb, col=jglob) in a group slab (halfs)
  const int exoff = (jglob >> 5) * 512 + (((jglob >> 3) & 3) * 16 + pb) * 8 + (jglob & 7);

  _Float16* hbase = hbuf + grp * 8192;
  _Float16* cbase = cellbuf + grp * 8192;

  unsigned* slots = bar + grp * 64;  // 32 used per group
  unsigned bseq = 0;

  half8 wgf[4][8], wif[4][8];
  float st_c = 0.f, st_ci = 0.f, o_pre = 0.f;
  float bgv[4], biv[4];

  for (int l = 0; l < 2; ++l) {
    // ---- layer init: weights -> VGPR fp16 frags (wave wv: K cols [256wv,256wv+256)) ----
#pragma unroll
    for (int g = 0; g < 4; ++g) {
      const float* wgr = Wg + ((size_t)l * 2048 + g * 512 + ncol) * 1024 + wv * 256;
      const float* wir = Wi + ((size_t)l * 2048 + g * 512 + ncol) * 1024 + wv * 256;
#pragma unroll
      for (int i = 0; i < 8; ++i) {
        const float* p = wgr + i * 32 + kg * 8;
        wgf[g][i] = cvt8(*(const float4*)p, *(const float4*)(p + 4));
        const float* q = wir + i * 32 + kg * 8;
        wif[g][i] = cvt8(*(const float4*)q, *(const float4*)(q + 4));
      }
      bgv[g] = bgb[l * 2048 + g * 512 + jglob];
      biv[g] = bib[l * 2048 + g * 512 + jglob];
    }
    // states: h0[l] layout (h, c, h_inner, c_inner) each [B,H]
    const float* h0l = h0 + (size_t)l * 4 * B_DIM * H_DIM + (size_t)brow * H_DIM + jglob;
    float h_in  = h0l[0];
    st_c        = h0l[(size_t)1 * B_DIM * H_DIM];
    float hi_in = h0l[(size_t)2 * B_DIM * H_DIM];
    st_ci       = h0l[(size_t)3 * B_DIM * H_DIM];
    hbase[exoff] = (_Float16)h_in;
    hibuf[grp * 8192 + exoff] = (_Float16)hi_in;  // parity 0 read at t=0
    gbar_arrive(slots, bc, ++bseq);
    {  // ---- prestage x(t=0) -> Alds ks 0..15 (inside poll window) ----
      const int m   = tid & 15;
      const int kq  = (tid >> 4) & 3;
      const float* srow_p = (l == 0)
          ? xin + ((size_t)0 * B_DIM + grp * 16 + m) * C_DIM
          : out + ((size_t)0 * B_DIM + grp * 16 + m) * H_DIM;
#pragma unroll
      for (int i = 0; i < 4; ++i) {
        const int ks = wv + i * 4;
        const float* p = srow_p + ks * 32 + kq * 8;
        *(half8*)(AldsH + ks * 512 + (kq * 16 + m) * 8) =
            cvt8(*(const float4*)p, *(const float4*)(p + 4));
      }
    }
    gbar_wait(slots, bseq);

    for (int t = 0; t < T_DIM; ++t) {
      // ---- stage h -> Alds ks 16..31 (contiguous 16KB copy) ----
#pragma unroll
      for (int i = 0; i < 4; ++i) {
        const int idx = i * 256 + tid;
        *(uint4*)(AldsH + 8192 + idx * 8) = *(const uint4*)(hbase + idx * 8);
      }
      __syncthreads();
      {  // ---- MFMA 1: wave wv's K-slice of g = [x|h] @ Wg^T, all 4 gates ----
        f32x4 acc[4];
#pragma unroll
        for (int g = 0; g < 4; ++g) acc[g] = (f32x4){0.f, 0.f, 0.f, 0.f};
#pragma unroll
        for (int i = 0; i < 8; ++i) {
          half8 a = *(const half8*)(AldsH + (wv * 8 + i) * 512 + lane * 8);
#pragma unroll
          for (int g = 0; g < 4; ++g)
            acc[g] = __builtin_amdgcn_mfma_f32_16x16x32_f16(a, wgf[g][i], acc[g], 0, 0, 0);
        }
#pragma unroll
        for (int g = 0; g < 4; ++g)
#pragma unroll
          for (int rr = 0; rr < 4; ++rr)
            Pl[((g * 16 + kg * 4 + rr) * 16 + ln) * 4 + (wv ^ kg)] = acc[g][rr];
      }
      __syncthreads();
      {  // ---- pointwise 1: reduce 4 K-partials; cell = sig(f)*c + sig(i)*tanh(gc) ----
        f32x4 v0 = *(const f32x4*)(Pl + ((0 * 16 + pb) * 16 + pj) * 4);
        f32x4 v1 = *(const f32x4*)(Pl + ((1 * 16 + pb) * 16 + pj) * 4);
        f32x4 v2 = *(const f32x4*)(Pl + ((2 * 16 + pb) * 16 + pj) * 4);
        f32x4 v3 = *(const f32x4*)(Pl + ((3 * 16 + pb) * 16 + pj) * 4);
        float gi = v0[0] + v0[1] + v0[2] + v0[3] + bgv[0];
        float gf = v1[0] + v1[1] + v1[2] + v1[3] + bgv[1];
        float go = v2[0] + v2[1] + v2[2] + v2[3] + bgv[2];
        float gc = v3[0] + v3[1] + v3[2] + v3[3] + bgv[3];
        float cell = sigf(gf) * st_c + sigf(gi) * tanhf_(gc);
        o_pre = go;
        cbase[exoff] = (_Float16)cell;
      }
      gbar_arrive(slots, bc, ++bseq);  // cell barrier: arrive
      {  // ---- prestage hi -> Alds ks 16..31 (inside poll window) ----
        const _Float16* hird = hibuf + (size_t)(t & 1) * 65536 + grp * 8192;
#pragma unroll
        for (int i = 0; i < 4; ++i) {
          const int idx = i * 256 + tid;
          *(uint4*)(AldsH + 8192 + idx * 8) = *(const uint4*)(hird + idx * 8);
        }
      }
      gbar_wait(slots, bseq);  // cell visible group-wide

      // ---- stage cell -> Alds ks 0..15 (contiguous 16KB copy) ----
#pragma unroll
      for (int i = 0; i < 4; ++i) {
        const int idx = i * 256 + tid;
        *(uint4*)(AldsH + idx * 8) = *(const uint4*)(cbase + idx * 8);
      }
      __syncthreads();
      {  // ---- MFMA 2: wave wv's K-slice of g2 = [cell|hi] @ Wi^T ----
        f32x4 acc[4];
#pragma unroll
        for (int g = 0; g < 4; ++g) acc[g] = (f32x4){0.f, 0.f, 0.f, 0.f};
#pragma unroll
        for (int i = 0; i < 8; ++i) {
          half8 a = *(const half8*)(AldsH + (wv * 8 + i) * 512 + lane * 8);
#pragma unroll
          for (int g = 0; g < 4; ++g)
            acc[g] = __builtin_amdgcn_mfma_f32_16x16x32_f16(a, wif[g][i], acc[g], 0, 0, 0);
        }
#pragma unroll
        for (int g = 0; g < 4; ++g)
#pragma unroll
          for (int rr = 0; rr < 4; ++rr)
            Pl[((g * 16 + kg * 4 + rr) * 16 + ln) * 4 + (wv ^ kg)] = acc[g][rr];
      }
      __syncthreads();
      {  // ---- pointwise 2: reduce partials; inner cell; outputs; c := hi_n ----
        f32x4 v0 = *(const f32x4*)(Pl + ((0 * 16 + pb) * 16 + pj) * 4);
        f32x4 v1 = *(const f32x4*)(Pl + ((1 * 16 + pb) * 16 + pj) * 4);
        f32x4 v2 = *(const f32x4*)(Pl + ((2 * 16 + pb) * 16 + pj) * 4);
        f32x4 v3 = *(const f32x4*)(Pl + ((3 * 16 + pb) * 16 + pj) * 4);
        float i2 = v0[0] + v0[1] + v0[2] + v0[3] + biv[0];
        float f2 = v1[0] + v1[1] + v1[2] + v1[3] + biv[1];
        float o2 = v2[0] + v2[1] + v2[2] + v2[3] + biv[2];
        float c2 = v3[0] + v3[1] + v3[2] + v3[3] + biv[3];
        float ci_n = sigf(f2) * st_ci + sigf(i2) * tanhf_(c2);
        float hi_n = sigf(o2) * tanhf_(ci_n);
        float h_n  = sigf(o_pre) * tanhf_(hi_n);
        st_ci = ci_n;
        st_c  = hi_n;  // reference: carry c <- hi_n
        hibuf[(size_t)((t + 1) & 1) * 65536 + grp * 8192 + exoff] = (_Float16)hi_n;
        hbase[exoff] = (_Float16)h_n;
        out[((size_t)t * B_DIM + brow) * H_DIM + jglob] = h_n;  // l0: y0, l1: final
      }
      gbar_arrive(slots, bc, ++bseq);  // h barrier: arrive
      if (t + 1 < T_DIM) {  // ---- prestage x(t+1) -> Alds ks 0..15 (poll window) ----
        const int m   = tid & 15;
        const int kq  = (tid >> 4) & 3;
        const float* srow_p = (l == 0)
            ? xin + ((size_t)(t + 1) * B_DIM + grp * 16 + m) * C_DIM
            : out + ((size_t)(t + 1) * B_DIM + grp * 16 + m) * H_DIM;
#pragma unroll
        for (int i = 0; i < 4; ++i) {
          const int ks = wv + i * 4;
          const float* p = srow_p + ks * 32 + kq * 8;
          *(half8*)(AldsH + ks * 512 + (kq * 16 + m) * 8) =
              cvt8(*(const float4*)p, *(const float4*)(p + 4));
        }
      }
      gbar_wait(slots, bseq);  // h/hi visible for next step
    }
  }
}

extern "C" void kernel_launch(void* const* d_in, const int* in_sizes, int n_in,
                              void* d_out, int out_size, void* d_ws, size_t ws_size,
                              hipStream_t stream) {
  const float* xin = (const float*)d_in[0];
  const float* h0  = (const float*)d_in[1];
  const float* Wg  = (const float*)d_in[2];
  const float* bg  = (const float*)d_in[3];
  const float* Wi  = (const float*)d_in[4];
  const float* bi  = (const float*)d_in[5];
  float* out = (float*)d_out;

  // ws: [0,4KB) epoch slots (8 groups x 256B); hbuf fp16 [8][8192] (128KB);
  // hibuf fp16 [2][8][8192] (256KB); cellbuf fp16 [8][8192] (128KB). ~516KB.
  unsigned* bar   = (unsigned*)d_ws;
  _Float16* hbuf  = (_Float16*)((char*)d_ws + 4096);
  _Float16* hibuf = hbuf + (size_t)8 * 8192;
  _Float16* cellb = hibuf + (size_t)2 * 8 * 8192;

  hipMemsetAsync(d_ws, 0, 4096, stream);  // epoch slots must start at 0

  nlstm_pers<<<dim3(256), dim3(256), 0, stream>>>(
      xin, h0, Wg, bg, Wi, bi, out, bar, hbuf, hibuf, cellb);
}